// Round 13
// baseline (54.079 us; speedup 1.0000x reference)
//
#include <hip/hip_runtime.h>
#include <math.h>

// Chamfer distance via MFMA, B=8, N=8192, fp32 in, fp32 scalar out.
//
// d(q,t) = |q|^2 + |t|^2 - 2 q.t  ==  dot(A_row(q), B_col(t)) with K=5:
//   A_row = (-2x_q, -2y_q, -2z_q, 1, |q|^2),  B_col = (x_t, y_t, z_t, |t|^2, 1)
// in f16 (zero-padded to K=16).  One v_mfma_f32_32x32x16_f16 -> a 32x32 tile
// of complete squared distances in fp32.
//
// prep:   both clouds -> packed f16 form (x,y,z,n,1,0,0,0) + init bits buf.
// main:   4096 blocks = dir(2) x batch(8) x rowblock(64) x colsplit(4).
//         256 thr = 4 waves, each wave one 32-row strip; block covers
//         128 rows x 2048 cols.  The whole 2048-col B-slab (32 KB) is
//         staged ONCE -> a single __syncthreads, then a ROLLED 32-iter
//         loop (unroll 1: bounded live ranges, no R6/R7 spills).  Waves
//         free-run and de-phase via matrix-pipe contention, overlapping
//         one wave's fmin fold with another's MFMA (counters showed both
//         pipes at their floor but phase-separated by per-chunk barriers).
// reduce: lane-min + atomicMin bits merge, then sqrt+sum+scale.

#define NPTS   8192
#define NB     8
#define NPC    (NB * NPTS)         // 65536
#define BLOCK  256
#define CS     4                   // col splits
#define COLS   (NPTS / CS)         // 2048 cols per block
#define TOTALQ (2 * NPC)           // 131072
#define EPSV   1e-12f

typedef _Float16 v8h  __attribute__((ext_vector_type(8)));
typedef float    v16f __attribute__((ext_vector_type(16)));

__global__ __launch_bounds__(256) void chamfer_prep(
    const float* __restrict__ xyz1, const float* __restrict__ xyz2,
    v8h* __restrict__ form, unsigned* __restrict__ bits)
{
    const int gid = blockIdx.x * 256 + threadIdx.x;      // [0, TOTALQ)
    const float* __restrict__ src = (gid < NPC) ? xyz1 : xyz2;
    const int i = (gid < NPC) ? gid : gid - NPC;
    float x = src[3 * i], y = src[3 * i + 1], z = src[3 * i + 2];
    _Float16 xh = (_Float16)x, yh = (_Float16)y, zh = (_Float16)z;
    float xf = (float)xh, yf = (float)yh, zf = (float)zh;
    float n = fmaf(xf, xf, fmaf(yf, yf, zf * zf));
    v8h bv = {};
    bv[0] = xh; bv[1] = yh; bv[2] = zh;
    bv[3] = (_Float16)n; bv[4] = (_Float16)1.0f;
    form[gid] = bv;
    bits[gid] = 0x7F7F7F7FU;       // 3.39e38f: "+inf" for nonneg uint-min
}

#define MFMA(va, vb) __builtin_amdgcn_mfma_f32_32x32x16_f16((va), (vb), vzero, 0, 0, 0)

__global__ __launch_bounds__(BLOCK, 4) void chamfer_mfma_min(
    const v8h* __restrict__ form, unsigned* __restrict__ bits)
{
    const int bid = blockIdx.x;             // [0, 4096)
    const int cs  = bid & (CS - 1);
    const int rb  = (bid >> 2) & 63;
    const int b   = (bid >> 8) & 7;
    const int dir = (bid >> 11) & 1;

    const v8h* __restrict__ qf = form + (size_t)dir * NPC + (size_t)b * NPTS;
    const v8h* __restrict__ tf = form + (size_t)(1 - dir) * NPC
                                      + (size_t)b * NPTS + cs * COLS;

    const int tid  = threadIdx.x;
    const int lane = tid & 63;
    const int w    = tid >> 6;              // wave 0..3, one 32-row strip each
    const int c31  = lane & 31;
    const int rowbase = rb * 128;

    // Stage the block's entire 2048-col B-slab once (32 KB).
    __shared__ v8h bsh[COLS];
#pragma unroll
    for (int k = 0; k < COLS / BLOCK; ++k)
        bsh[k * BLOCK + tid] = tf[k * BLOCK + tid];      // b128 in, b128 out

    // A fragment: lanes<32 carry k=0..7 (5 live slots); lanes>=32 carry
    // k=8..15 which are all zero.
    v8h a0 = {};
    if (lane < 32) {
        const _Float16 m2 = (_Float16)(-2.0f);
        v8h f = qf[rowbase + w * 32 + lane];
        a0[0] = m2 * f[0]; a0[1] = m2 * f[1]; a0[2] = m2 * f[2];
        a0[3] = (_Float16)1.0f; a0[4] = f[3];
    }

    float rm0[16];
#pragma unroll
    for (int r = 0; r < 16; ++r) rm0[r] = 3.4e38f;

    const v16f vzero = {};
    __syncthreads();                        // the only barrier

    // Rolled loop: bounded live ranges (no spill), waves free-run.
#pragma unroll 1
    for (int cc = 0; cc < COLS / 64; ++cc) {
        const v8h b0 = bsh[cc * 64 + c31];               // broadcast b128
        const v8h b1 = bsh[cc * 64 + 32 + c31];
        v16f p = MFMA(a0, b0);
        v16f q = MFMA(a0, b1);
#pragma unroll
        for (int r = 0; r < 16; ++r)
            rm0[r] = fminf(fminf(rm0[r], p[r]), q[r]);
    }

    // Butterfly row-min across the 32 lanes sharing each row, then one
    // atomicMin per row (nonneg-float uint order; exact, deterministic).
    unsigned* dst = bits + (size_t)(dir * NB + b) * NPTS + rowbase;
#pragma unroll
    for (int r = 0; r < 16; ++r) {
        float v = rm0[r];
        v = fminf(v, __shfl_xor(v, 1));
        v = fminf(v, __shfl_xor(v, 2));
        v = fminf(v, __shfl_xor(v, 4));
        v = fminf(v, __shfl_xor(v, 8));
        v = fminf(v, __shfl_xor(v, 16));
        if ((lane & 31) == 0) {
            int row_local = w * 32 + (r & 3) + 8 * (r >> 2) + 4 * (lane >> 5);
            atomicMin(dst + row_local, __float_as_uint(fmaxf(v, 0.0f)));
        }
    }
}

__global__ __launch_bounds__(256) void chamfer_reduce1(
    const unsigned* __restrict__ bits,   // [TOTALQ]
    float* __restrict__ sums)            // [512]
{
    const int idx = blockIdx.x * 256 + threadIdx.x;
    float m = __uint_as_float(bits[idx]);
    float val = sqrtf(fmaxf(m, EPSV));

    __shared__ float red[256];
    red[threadIdx.x] = val;
    __syncthreads();
    for (int s = 128; s > 0; s >>= 1) {
        if (threadIdx.x < s) red[threadIdx.x] += red[threadIdx.x + s];
        __syncthreads();
    }
    if (threadIdx.x == 0) sums[blockIdx.x] = red[0];
}

#define NSUMS (TOTALQ / 256)   // 512

__global__ __launch_bounds__(NSUMS) void chamfer_finalize(
    const float* __restrict__ sums, float* __restrict__ out)
{
    __shared__ float red[NSUMS];
    red[threadIdx.x] = sums[threadIdx.x];
    __syncthreads();
    for (int s = NSUMS / 2; s > 0; s >>= 1) {
        if (threadIdx.x < s) red[threadIdx.x] += red[threadIdx.x + s];
        __syncthreads();
    }
    if (threadIdx.x == 0) out[0] = red[0] * (1.0f / (float)TOTALQ);
}

extern "C" void kernel_launch(void* const* d_in, const int* in_sizes, int n_in,
                              void* d_out, int out_size, void* d_ws, size_t ws_size,
                              hipStream_t stream) {
    const float* xyz1 = (const float*)d_in[0];
    const float* xyz2 = (const float*)d_in[1];
    float* out = (float*)d_out;

    v8h*      formbuf = (v8h*)d_ws;                      // TOTALQ v8h = 2 MB
    unsigned* bitsbuf = (unsigned*)(formbuf + TOTALQ);   // TOTALQ u32 = 512 KB
    float*    sums    = (float*)(bitsbuf + TOTALQ);      // 512 floats

    chamfer_prep<<<TOTALQ / 256, 256, 0, stream>>>(xyz1, xyz2, formbuf, bitsbuf);
    chamfer_mfma_min<<<2 * NB * 64 * CS, BLOCK, 0, stream>>>(formbuf, bitsbuf);
    chamfer_reduce1<<<TOTALQ / 256, 256, 0, stream>>>(bitsbuf, sums);
    chamfer_finalize<<<1, NSUMS, 0, stream>>>(sums, out);
}

// Round 14
// 47.648 us; speedup vs baseline: 1.1350x; 1.1350x over previous
//
#include <hip/hip_runtime.h>
#include <math.h>

// Chamfer distance via MFMA, B=8, N=8192, fp32 in, fp32 scalar out.
//
// d(q,t) = |q|^2 + |t|^2 - 2 q.t  ==  dot(A_row(q), B_col(t)) with K=5:
//   A_row = (-2x_q, -2y_q, -2z_q, 1, |q|^2),  B_col = (x_t, y_t, z_t, |t|^2, 1)
// in f16 (zero-padded to K=16).  One v_mfma_f32_32x32x16_f16 -> a 32x32 tile
// of complete squared distances in fp32.
//
// prep:   both clouds -> packed f16 form (x,y,z,n,1,0,0,0) + init bits buf.
// main:   1024 blocks = dir(2) x batch(8) x rowblock(32) x colsplit(2),
//         512 threads = 8 waves; each wave owns ONE 32-row strip (low
//         register footprint ~55 VGPR).  __launch_bounds__(512,6) raises
//         residency to ~24 waves/CU so cross-wave overlap fills the
//         matrix+VALU pipes (R9/R10/R12 lesson: intra-wave scheduling is
//         either re-serialized, races MFMA writeback, or spills).
// reduce: lane-min + atomicMin bits merge, then sqrt+sum+scale.

#define NPTS   8192
#define NB     8
#define NPC    (NB * NPTS)         // 65536
#define BLOCK  512
#define CHUNK  1024
#define CS     2                   // col splits
#define COLS   (NPTS / CS)         // 4096 cols per block
#define TOTALQ (2 * NPC)           // 131072
#define EPSV   1e-12f

typedef _Float16 v8h  __attribute__((ext_vector_type(8)));
typedef float    v16f __attribute__((ext_vector_type(16)));

__global__ __launch_bounds__(256) void chamfer_prep(
    const float* __restrict__ xyz1, const float* __restrict__ xyz2,
    v8h* __restrict__ form, unsigned* __restrict__ bits)
{
    const int gid = blockIdx.x * 256 + threadIdx.x;      // [0, TOTALQ)
    const float* __restrict__ src = (gid < NPC) ? xyz1 : xyz2;
    const int i = (gid < NPC) ? gid : gid - NPC;
    float x = src[3 * i], y = src[3 * i + 1], z = src[3 * i + 2];
    _Float16 xh = (_Float16)x, yh = (_Float16)y, zh = (_Float16)z;
    float xf = (float)xh, yf = (float)yh, zf = (float)zh;
    float n = fmaf(xf, xf, fmaf(yf, yf, zf * zf));
    v8h bv = {};
    bv[0] = xh; bv[1] = yh; bv[2] = zh;
    bv[3] = (_Float16)n; bv[4] = (_Float16)1.0f;
    form[gid] = bv;
    bits[gid] = 0x7F7F7F7FU;       // 3.39e38f: "+inf" for nonneg uint-min
}

#define MFMA(va, vb) __builtin_amdgcn_mfma_f32_32x32x16_f16((va), (vb), vzero, 0, 0, 0)

__global__ __launch_bounds__(BLOCK, 6) void chamfer_mfma_min(
    const v8h* __restrict__ form, unsigned* __restrict__ bits)
{
    const int bid = blockIdx.x;             // [0, 1024)
    const int cs  = bid & (CS - 1);
    const int rb  = (bid >> 1) & 31;
    const int b   = (bid >> 6) & 7;
    const int dir = (bid >> 9) & 1;

    const v8h* __restrict__ qf = form + (size_t)dir * NPC + (size_t)b * NPTS;
    const v8h* __restrict__ tf = form + (size_t)(1 - dir) * NPC
                                      + (size_t)b * NPTS + cs * COLS;

    const int tid  = threadIdx.x;
    const int lane = tid & 63;
    const int w    = tid >> 6;              // wave 0..7, one 32-row strip each
    const int c31  = lane & 31;
    const int rowbase = rb * 256;

    // A fragment: lanes<32 carry k=0..7 (5 live slots); lanes>=32 carry
    // k=8..15 which are all zero.
    v8h a0 = {};
    if (lane < 32) {
        const _Float16 m2 = (_Float16)(-2.0f);
        v8h f = qf[rowbase + w * 32 + lane];
        a0[0] = m2 * f[0]; a0[1] = m2 * f[1]; a0[2] = m2 * f[2];
        a0[3] = (_Float16)1.0f; a0[4] = f[3];
    }

    float rm0[16];
#pragma unroll
    for (int r = 0; r < 16; ++r) rm0[r] = 3.4e38f;

    __shared__ v8h bsh[CHUNK];              // 16 KB
    const v16f vzero = {};

    for (int ch = 0; ch < COLS / CHUNK; ++ch) {
        __syncthreads();
        const v8h* __restrict__ g = tf + ch * CHUNK;
#pragma unroll
        for (int k = 0; k < CHUNK / BLOCK; ++k)
            bsh[k * BLOCK + tid] = g[k * BLOCK + tid];   // b128 in, b128 out
        __syncthreads();

#pragma unroll
        for (int cc = 0; cc < CHUNK / 64; ++cc) {
            const v8h b0 = bsh[cc * 64 + c31];           // broadcast b128
            const v8h b1 = bsh[cc * 64 + 32 + c31];
            v16f p = MFMA(a0, b0);
            v16f q = MFMA(a0, b1);
#pragma unroll
            for (int r = 0; r < 16; ++r)
                rm0[r] = fminf(fminf(rm0[r], p[r]), q[r]);
        }
    }

    // Butterfly row-min across the 32 lanes sharing each row, then one
    // atomicMin per row (nonneg-float uint order; exact, deterministic).
    unsigned* dst = bits + (size_t)(dir * NB + b) * NPTS + rowbase;
#pragma unroll
    for (int r = 0; r < 16; ++r) {
        float v = rm0[r];
        v = fminf(v, __shfl_xor(v, 1));
        v = fminf(v, __shfl_xor(v, 2));
        v = fminf(v, __shfl_xor(v, 4));
        v = fminf(v, __shfl_xor(v, 8));
        v = fminf(v, __shfl_xor(v, 16));
        if ((lane & 31) == 0) {
            int row_local = w * 32 + (r & 3) + 8 * (r >> 2) + 4 * (lane >> 5);
            atomicMin(dst + row_local, __float_as_uint(fmaxf(v, 0.0f)));
        }
    }
}

__global__ __launch_bounds__(256) void chamfer_reduce1(
    const unsigned* __restrict__ bits,   // [TOTALQ]
    float* __restrict__ sums)            // [512]
{
    const int idx = blockIdx.x * 256 + threadIdx.x;
    float m = __uint_as_float(bits[idx]);
    float val = sqrtf(fmaxf(m, EPSV));

    __shared__ float red[256];
    red[threadIdx.x] = val;
    __syncthreads();
    for (int s = 128; s > 0; s >>= 1) {
        if (threadIdx.x < s) red[threadIdx.x] += red[threadIdx.x + s];
        __syncthreads();
    }
    if (threadIdx.x == 0) sums[blockIdx.x] = red[0];
}

#define NSUMS (TOTALQ / 256)   // 512

__global__ __launch_bounds__(NSUMS) void chamfer_finalize(
    const float* __restrict__ sums, float* __restrict__ out)
{
    __shared__ float red[NSUMS];
    red[threadIdx.x] = sums[threadIdx.x];
    __syncthreads();
    for (int s = NSUMS / 2; s > 0; s >>= 1) {
        if (threadIdx.x < s) red[threadIdx.x] += red[threadIdx.x + s];
        __syncthreads();
    }
    if (threadIdx.x == 0) out[0] = red[0] * (1.0f / (float)TOTALQ);
}

extern "C" void kernel_launch(void* const* d_in, const int* in_sizes, int n_in,
                              void* d_out, int out_size, void* d_ws, size_t ws_size,
                              hipStream_t stream) {
    const float* xyz1 = (const float*)d_in[0];
    const float* xyz2 = (const float*)d_in[1];
    float* out = (float*)d_out;

    v8h*      formbuf = (v8h*)d_ws;                      // TOTALQ v8h = 2 MB
    unsigned* bitsbuf = (unsigned*)(formbuf + TOTALQ);   // TOTALQ u32 = 512 KB
    float*    sums    = (float*)(bitsbuf + TOTALQ);      // 512 floats

    chamfer_prep<<<TOTALQ / 256, 256, 0, stream>>>(xyz1, xyz2, formbuf, bitsbuf);
    chamfer_mfma_min<<<2 * NB * 32 * CS, BLOCK, 0, stream>>>(formbuf, bitsbuf);
    chamfer_reduce1<<<TOTALQ / 256, 256, 0, stream>>>(bitsbuf, sums);
    chamfer_finalize<<<1, NSUMS, 0, stream>>>(sums, out);
}

// Round 15
// 46.564 us; speedup vs baseline: 1.1614x; 1.0233x over previous
//
#include <hip/hip_runtime.h>
#include <math.h>

// Chamfer distance via MFMA, B=8, N=8192, fp32 in, fp32 scalar out.
//
// d(q,t) = |q|^2 + |t|^2 - 2 q.t  ==  dot(A_row(q), B_col(t)) with K=5:
//   A_row = (-2x_q, -2y_q, -2z_q, 1, |q|^2),  B_col = (x_t, y_t, z_t, |t|^2, 1)
// in f16 (zero-padded to K=16).  One v_mfma_f32_32x32x16_f16 -> a 32x32 tile
// of complete squared distances in fp32.
//
// prep:   both clouds -> packed f16 form (x,y,z,n,1,0,0,0); zero sum counter.
// main:   512 blocks = dir(2) x batch(8) x rowblock(32); 8 waves each own
//         one 32-row strip and scan ALL 8192 cols (CS=1) -> rowmins are
//         block-final, so the epilogue does sqrt + block-sum directly and
//         merges with ONE u64 fixed-point atomicAdd per block (order-
//         independent => deterministic).  No bits buffer, no atomicMin
//         pass, no reduce kernel.  setprio(1) wraps the MFMA pair (T5:
//         free-running waves have role diversity for the CU scheduler).
// final:  1 thread: out = counter / 2^26 / TOTALQ.

#define NPTS   8192
#define NB     8
#define NPC    (NB * NPTS)         // 65536
#define BLOCK  512
#define CHUNK  1024
#define COLS   NPTS                // all cols per block
#define TOTALQ (2 * NPC)           // 131072
#define EPSV   1e-12f
#define FXSCALE 67108864.0         // 2^26

typedef _Float16 v8h  __attribute__((ext_vector_type(8)));
typedef float    v16f __attribute__((ext_vector_type(16)));

__global__ __launch_bounds__(256) void chamfer_prep(
    const float* __restrict__ xyz1, const float* __restrict__ xyz2,
    v8h* __restrict__ form, unsigned long long* __restrict__ counter)
{
    const int gid = blockIdx.x * 256 + threadIdx.x;      // [0, TOTALQ)
    if (gid == 0) counter[0] = 0ULL;
    const float* __restrict__ src = (gid < NPC) ? xyz1 : xyz2;
    const int i = (gid < NPC) ? gid : gid - NPC;
    float x = src[3 * i], y = src[3 * i + 1], z = src[3 * i + 2];
    _Float16 xh = (_Float16)x, yh = (_Float16)y, zh = (_Float16)z;
    float xf = (float)xh, yf = (float)yh, zf = (float)zh;
    float n = fmaf(xf, xf, fmaf(yf, yf, zf * zf));
    v8h bv = {};
    bv[0] = xh; bv[1] = yh; bv[2] = zh;
    bv[3] = (_Float16)n; bv[4] = (_Float16)1.0f;
    form[gid] = bv;
}

#define MFMA(va, vb) __builtin_amdgcn_mfma_f32_32x32x16_f16((va), (vb), vzero, 0, 0, 0)

__global__ __launch_bounds__(BLOCK, 4) void chamfer_mfma_min(
    const v8h* __restrict__ form, unsigned long long* __restrict__ counter)
{
    const int bid = blockIdx.x;             // [0, 512)
    const int rb  = bid & 31;
    const int b   = (bid >> 5) & 7;
    const int dir = (bid >> 8) & 1;

    const v8h* __restrict__ qf = form + (size_t)dir * NPC + (size_t)b * NPTS;
    const v8h* __restrict__ tf = form + (size_t)(1 - dir) * NPC + (size_t)b * NPTS;

    const int tid  = threadIdx.x;
    const int lane = tid & 63;
    const int w    = tid >> 6;              // wave 0..7, one 32-row strip each
    const int c31  = lane & 31;
    const int rowbase = rb * 256;

    // A fragment: lanes<32 carry k=0..7 (5 live slots); lanes>=32 carry
    // k=8..15 which are all zero.
    v8h a0 = {};
    if (lane < 32) {
        const _Float16 m2 = (_Float16)(-2.0f);
        v8h f = qf[rowbase + w * 32 + lane];
        a0[0] = m2 * f[0]; a0[1] = m2 * f[1]; a0[2] = m2 * f[2];
        a0[3] = (_Float16)1.0f; a0[4] = f[3];
    }

    float rm0[16];
#pragma unroll
    for (int r = 0; r < 16; ++r) rm0[r] = 3.4e38f;

    __shared__ v8h bsh[CHUNK];              // 16 KB
    const v16f vzero = {};

    for (int ch = 0; ch < COLS / CHUNK; ++ch) {
        __syncthreads();
        const v8h* __restrict__ g = tf + ch * CHUNK;
#pragma unroll
        for (int k = 0; k < CHUNK / BLOCK; ++k)
            bsh[k * BLOCK + tid] = g[k * BLOCK + tid];   // b128 in, b128 out
        __syncthreads();

#pragma unroll
        for (int cc = 0; cc < CHUNK / 64; ++cc) {
            const v8h b0 = bsh[cc * 64 + c31];           // broadcast b128
            const v8h b1 = bsh[cc * 64 + 32 + c31];
            __builtin_amdgcn_s_setprio(1);
            v16f p = MFMA(a0, b0);
            v16f q = MFMA(a0, b1);
            __builtin_amdgcn_s_setprio(0);
#pragma unroll
            for (int r = 0; r < 16; ++r)
                rm0[r] = fminf(fminf(rm0[r], p[r]), q[r]);
        }
    }

    // Epilogue: butterfly row-min across the 32 lanes sharing each row
    // (rowmins are FINAL here: this block saw all 8192 cols), then sqrt,
    // per-block sum, one u64 fixed-point atomicAdd (deterministic).
    float acc = 0.0f;
#pragma unroll
    for (int r = 0; r < 16; ++r) {
        float v = rm0[r];
        v = fminf(v, __shfl_xor(v, 1));
        v = fminf(v, __shfl_xor(v, 2));
        v = fminf(v, __shfl_xor(v, 4));
        v = fminf(v, __shfl_xor(v, 8));
        v = fminf(v, __shfl_xor(v, 16));
        if ((lane & 31) == 0)
            acc += sqrtf(fmaxf(fmaxf(v, 0.0f), EPSV));   // lanes 0,32 only (else acc stays 0)
    }
    acc += __shfl_xor(acc, 32);             // lane 0: sum of this wave's 32 rows

    __syncthreads();                        // safe to reuse bsh
    float* red = (float*)bsh;
    if (lane == 0) red[w] = acc;
    __syncthreads();
    if (tid == 0) {
        float s = red[0] + red[1] + red[2] + red[3]
                + red[4] + red[5] + red[6] + red[7];
        unsigned long long fx = (unsigned long long)((double)s * FXSCALE + 0.5);
        atomicAdd(counter, fx);
    }
}

__global__ void chamfer_finalize(
    const unsigned long long* __restrict__ counter, float* __restrict__ out)
{
    out[0] = (float)((double)counter[0] * (1.0 / FXSCALE) / (double)TOTALQ);
}

extern "C" void kernel_launch(void* const* d_in, const int* in_sizes, int n_in,
                              void* d_out, int out_size, void* d_ws, size_t ws_size,
                              hipStream_t stream) {
    const float* xyz1 = (const float*)d_in[0];
    const float* xyz2 = (const float*)d_in[1];
    float* out = (float*)d_out;

    v8h* formbuf = (v8h*)d_ws;                                   // TOTALQ v8h = 2 MB
    unsigned long long* counter = (unsigned long long*)(formbuf + TOTALQ);

    chamfer_prep<<<TOTALQ / 256, 256, 0, stream>>>(xyz1, xyz2, formbuf, counter);
    chamfer_mfma_min<<<2 * NB * 32, BLOCK, 0, stream>>>(formbuf, counter);
    chamfer_finalize<<<1, 1, 0, stream>>>(counter, out);
}

// Round 16
// 45.565 us; speedup vs baseline: 1.1869x; 1.0219x over previous
//
#include <hip/hip_runtime.h>
#include <math.h>

// Chamfer distance via MFMA, B=8, N=8192, fp32 in, fp32 scalar out.
//
// d(q,t) = |q|^2 + |t|^2 - 2 q.t  ==  dot(A_row(q), B_col(t)) with K=5:
//   A_row = (-2x_q, -2y_q, -2z_q, 1, |q|^2),  B_col = (x_t, y_t, z_t, |t|^2, 1)
// in f16 (zero-padded to K=16).  One v_mfma_f32_32x32x16_f16 -> a 32x32 tile
// of complete squared distances in fp32.
//
// Pipe-floor analysis (R14): LDS 20.5 us > MFMA 13.7 > fold-VALU 13.6.
// This round halves the two biggest:
//   - 2 row-strips per wave: each ds_read_b128 pair feeds 4 MFMAs -> LDS 10.2
//   - u32 min fold (squared dists are uint-monotone; negatives lose umin
//     harmlessly): umin chains fuse to v_min3_u32 (fminf won't fuse: NaN
//     semantics) -> fold VALU ~7 us.  No inline asm (R5/R10 hazard lesson).
//
// prep:   clouds -> packed f16 form (x,y,z,n,1,0,0,0); zero sum counter.
// main:   512 blocks = dir(2) x batch(8) x rowblock(32); 4 waves x 2 strips
//         = 256 rows/block, all 8192 cols -> rowmins block-final; epilogue
//         does sqrt + block-sum + ONE u64 fixed-point atomicAdd per block
//         (order-independent => deterministic).
// final:  1 thread: out = counter / 2^26 / TOTALQ.

#define NPTS   8192
#define NB     8
#define NPC    (NB * NPTS)         // 65536
#define BLOCK  256
#define CHUNK  1024
#define COLS   NPTS                // all cols per block
#define TOTALQ (2 * NPC)           // 131072
#define EPSV   1e-12f
#define FXSCALE 67108864.0         // 2^26

typedef _Float16 v8h  __attribute__((ext_vector_type(8)));
typedef float    v16f __attribute__((ext_vector_type(16)));

__global__ __launch_bounds__(256) void chamfer_prep(
    const float* __restrict__ xyz1, const float* __restrict__ xyz2,
    v8h* __restrict__ form, unsigned long long* __restrict__ counter)
{
    const int gid = blockIdx.x * 256 + threadIdx.x;      // [0, TOTALQ)
    if (gid == 0) counter[0] = 0ULL;
    const float* __restrict__ src = (gid < NPC) ? xyz1 : xyz2;
    const int i = (gid < NPC) ? gid : gid - NPC;
    float x = src[3 * i], y = src[3 * i + 1], z = src[3 * i + 2];
    _Float16 xh = (_Float16)x, yh = (_Float16)y, zh = (_Float16)z;
    float xf = (float)xh, yf = (float)yh, zf = (float)zh;
    float n = fmaf(xf, xf, fmaf(yf, yf, zf * zf));
    v8h bv = {};
    bv[0] = xh; bv[1] = yh; bv[2] = zh;
    bv[3] = (_Float16)n; bv[4] = (_Float16)1.0f;
    form[gid] = bv;
}

#define MFMA(va, vb) __builtin_amdgcn_mfma_f32_32x32x16_f16((va), (vb), vzero, 0, 0, 0)

__device__ __forceinline__ unsigned umin2(unsigned a, unsigned b) {
    return a < b ? a : b;
}

__global__ __launch_bounds__(BLOCK, 4) void chamfer_mfma_min(
    const v8h* __restrict__ form, unsigned long long* __restrict__ counter)
{
    const int bid = blockIdx.x;             // [0, 512)
    const int rb  = bid & 31;
    const int b   = (bid >> 5) & 7;
    const int dir = (bid >> 8) & 1;

    const v8h* __restrict__ qf = form + (size_t)dir * NPC + (size_t)b * NPTS;
    const v8h* __restrict__ tf = form + (size_t)(1 - dir) * NPC + (size_t)b * NPTS;

    const int tid  = threadIdx.x;
    const int lane = tid & 63;
    const int w    = tid >> 6;              // wave 0..3, two 32-row strips each
    const int c31  = lane & 31;
    const int rowbase = rb * 256;

    // A fragments: lanes<32 carry k=0..7 (5 live slots); lanes>=32 carry
    // k=8..15 which are all zero.
    v8h a0 = {}, a1 = {};
    if (lane < 32) {
        const _Float16 m2 = (_Float16)(-2.0f);
        v8h f = qf[rowbase + w * 64 + lane];
        a0[0] = m2 * f[0]; a0[1] = m2 * f[1]; a0[2] = m2 * f[2];
        a0[3] = (_Float16)1.0f; a0[4] = f[3];
        f = qf[rowbase + w * 64 + 32 + lane];
        a1[0] = m2 * f[0]; a1[1] = m2 * f[1]; a1[2] = m2 * f[2];
        a1[3] = (_Float16)1.0f; a1[4] = f[3];
    }

    unsigned rm0[16], rm1[16];
#pragma unroll
    for (int r = 0; r < 16; ++r) { rm0[r] = 0x7F7F7F7FU; rm1[r] = 0x7F7F7F7FU; }

    __shared__ v8h bsh[CHUNK];              // 16 KB
    const v16f vzero = {};

    for (int ch = 0; ch < COLS / CHUNK; ++ch) {
        __syncthreads();
        const v8h* __restrict__ g = tf + ch * CHUNK;
#pragma unroll
        for (int k = 0; k < CHUNK / BLOCK; ++k)
            bsh[k * BLOCK + tid] = g[k * BLOCK + tid];   // b128 in, b128 out
        __syncthreads();

#pragma unroll
        for (int cc = 0; cc < CHUNK / 64; ++cc) {
            const v8h b0 = bsh[cc * 64 + c31];           // broadcast b128
            const v8h b1 = bsh[cc * 64 + 32 + c31];
            __builtin_amdgcn_s_setprio(1);
            v16f p0 = MFMA(a0, b0);
            v16f q0 = MFMA(a0, b1);
            v16f p1 = MFMA(a1, b0);
            v16f q1 = MFMA(a1, b1);
            __builtin_amdgcn_s_setprio(0);
#pragma unroll
            for (int r = 0; r < 16; ++r)
                rm0[r] = umin2(rm0[r], umin2(__builtin_bit_cast(unsigned, p0[r]),
                                             __builtin_bit_cast(unsigned, q0[r])));
#pragma unroll
            for (int r = 0; r < 16; ++r)
                rm1[r] = umin2(rm1[r], umin2(__builtin_bit_cast(unsigned, p1[r]),
                                             __builtin_bit_cast(unsigned, q1[r])));
        }
    }

    // Epilogue: butterfly row-min across the 32 lanes sharing each row
    // (rowmins are FINAL: this block saw all 8192 cols), sqrt, block-sum,
    // one u64 fixed-point atomicAdd (order-independent => deterministic).
    float acc = 0.0f;
#pragma unroll
    for (int s = 0; s < 2; ++s) {
#pragma unroll
        for (int r = 0; r < 16; ++r) {
            unsigned u = s ? rm1[r] : rm0[r];
            u = umin2(u, __shfl_xor(u, 1));
            u = umin2(u, __shfl_xor(u, 2));
            u = umin2(u, __shfl_xor(u, 4));
            u = umin2(u, __shfl_xor(u, 8));
            u = umin2(u, __shfl_xor(u, 16));
            if ((lane & 31) == 0) {
                float v = __builtin_bit_cast(float, u);
                acc += sqrtf(fmaxf(fmaxf(v, 0.0f), EPSV));
            }
        }
    }
    acc += __shfl_xor(acc, 32);             // lane 0: this wave's 64 rows

    __syncthreads();                        // safe to reuse bsh
    float* red = (float*)bsh;
    if (lane == 0) red[w] = acc;
    __syncthreads();
    if (tid == 0) {
        float s = red[0] + red[1] + red[2] + red[3];
        unsigned long long fx = (unsigned long long)((double)s * FXSCALE + 0.5);
        atomicAdd(counter, fx);
    }
}

__global__ void chamfer_finalize(
    const unsigned long long* __restrict__ counter, float* __restrict__ out)
{
    out[0] = (float)((double)counter[0] * (1.0 / FXSCALE) / (double)TOTALQ);
}

extern "C" void kernel_launch(void* const* d_in, const int* in_sizes, int n_in,
                              void* d_out, int out_size, void* d_ws, size_t ws_size,
                              hipStream_t stream) {
    const float* xyz1 = (const float*)d_in[0];
    const float* xyz2 = (const float*)d_in[1];
    float* out = (float*)d_out;

    v8h* formbuf = (v8h*)d_ws;                                   // TOTALQ v8h = 2 MB
    unsigned long long* counter = (unsigned long long*)(formbuf + TOTALQ);

    chamfer_prep<<<TOTALQ / 256, 256, 0, stream>>>(xyz1, xyz2, formbuf, counter);
    chamfer_mfma_min<<<2 * NB * 32, BLOCK, 0, stream>>>(formbuf, counter);
    chamfer_finalize<<<1, 1, 0, stream>>>(counter, out);
}